// Round 1
// baseline (1099.827 us; speedup 1.0000x reference)
//
#include <hip/hip_runtime.h>

#define BATCH 64
#define TT    1024
#define INC   16
#define NN    512
#define RNK   16
#define OUTC  8

// a = DT/TAU = 0.1
#define A_COEF 0.1f

__device__ __forceinline__ float fast_tanh(float x) {
    // tanh(x) = 1 - 2/(exp(2x)+1); safe at +/-inf (no inf/inf)
    float e = __expf(2.0f * x);
    return 1.0f - __fdividef(2.0f, e + 1.0f);
}

// One block per batch element. 512 threads = 8 waves, one lane per state n.
// Weights live in registers for the whole scan; phi and low round-trip LDS.
__global__ __launch_bounds__(512, 1) void scan_kernel(
    const float* __restrict__ x,      // [B,T,INC]
    const float* __restrict__ In_w,   // [N,INC]
    const float* __restrict__ V_w,    // [R,N]
    const float* __restrict__ U_w,    // [N,R]
    const float* __restrict__ h0,     // [N]
    float* __restrict__ hidden)       // [B,T,N]
{
    const int b   = blockIdx.x;
    const int tid = threadIdx.x;
    const int n   = tid;
    const int rr  = tid >> 5;   // 0..15 : which low-rank row this lane reduces
    const int g   = tid & 31;   // 0..31 : position within the 32-lane reduce group

    // ---- per-lane weights in registers ----
    float Ur[RNK];
    #pragma unroll
    for (int r = 0; r < RNK; ++r) Ur[r] = U_w[n * RNK + r];

    float Wr[INC];
    #pragma unroll
    for (int i = 0; i < INC; ++i) Wr[i] = In_w[n * INC + i];

    // V fragment for the reduce phase: lane (rr,g) covers n' = k*128 + g*4 + j
    float Vr[16];
    #pragma unroll
    for (int k = 0; k < 4; ++k)
        #pragma unroll
        for (int j = 0; j < 4; ++j)
            Vr[k * 4 + j] = V_w[rr * NN + k * 128 + g * 4 + j];

    float h = h0[n];

    __shared__ __align__(16) float phi_s[NN];
    __shared__ __align__(16) float low_s[RNK];

    const float* xb = x + (size_t)b * TT * INC;
    float* hb = hidden + (size_t)b * TT * NN;

    for (int t = 0; t < TT; ++t) {
        // uniform-address x load (scalarizes to s_load)
        const float4* xp = (const float4*)(xb + t * INC);
        float4 x0 = xp[0], x1 = xp[1], x2 = xp[2], x3 = xp[3];

        float phi = fast_tanh(h);
        phi_s[tid] = phi;

        // input projection — independent of h, hides in barrier bubbles
        float inp;
        inp = Wr[0] * x0.x;
        inp = fmaf(Wr[1],  x0.y, inp);
        inp = fmaf(Wr[2],  x0.z, inp);
        inp = fmaf(Wr[3],  x0.w, inp);
        inp = fmaf(Wr[4],  x1.x, inp);
        inp = fmaf(Wr[5],  x1.y, inp);
        inp = fmaf(Wr[6],  x1.z, inp);
        inp = fmaf(Wr[7],  x1.w, inp);
        inp = fmaf(Wr[8],  x2.x, inp);
        inp = fmaf(Wr[9],  x2.y, inp);
        inp = fmaf(Wr[10], x2.z, inp);
        inp = fmaf(Wr[11], x2.w, inp);
        inp = fmaf(Wr[12], x3.x, inp);
        inp = fmaf(Wr[13], x3.y, inp);
        inp = fmaf(Wr[14], x3.z, inp);
        inp = fmaf(Wr[15], x3.w, inp);

        __syncthreads();

        // partial of low[rr] over this lane's 16 n's (4 strided float4 reads)
        float partial = 0.0f;
        #pragma unroll
        for (int k = 0; k < 4; ++k) {
            float4 p = *(const float4*)&phi_s[k * 128 + g * 4];
            partial = fmaf(Vr[k * 4 + 0], p.x, partial);
            partial = fmaf(Vr[k * 4 + 1], p.y, partial);
            partial = fmaf(Vr[k * 4 + 2], p.z, partial);
            partial = fmaf(Vr[k * 4 + 3], p.w, partial);
        }
        // butterfly over the 32-lane group (stays inside the wave)
        #pragma unroll
        for (int m = 1; m < 32; m <<= 1)
            partial += __shfl_xor(partial, m, 64);
        if (g == 0) low_s[rr] = partial;

        __syncthreads();

        // rec = U[n,:] . low  (low broadcast from LDS)
        float4 l0 = *(const float4*)&low_s[0];
        float4 l1 = *(const float4*)&low_s[4];
        float4 l2 = *(const float4*)&low_s[8];
        float4 l3 = *(const float4*)&low_s[12];
        float rec;
        rec = Ur[0] * l0.x;
        rec = fmaf(Ur[1],  l0.y, rec);
        rec = fmaf(Ur[2],  l0.z, rec);
        rec = fmaf(Ur[3],  l0.w, rec);
        rec = fmaf(Ur[4],  l1.x, rec);
        rec = fmaf(Ur[5],  l1.y, rec);
        rec = fmaf(Ur[6],  l1.z, rec);
        rec = fmaf(Ur[7],  l1.w, rec);
        rec = fmaf(Ur[8],  l2.x, rec);
        rec = fmaf(Ur[9],  l2.y, rec);
        rec = fmaf(Ur[10], l2.z, rec);
        rec = fmaf(Ur[11], l2.w, rec);
        rec = fmaf(Ur[12], l3.x, rec);
        rec = fmaf(Ur[13], l3.y, rec);
        rec = fmaf(Ur[14], l3.z, rec);
        rec = fmaf(Ur[15], l3.w, rec);

        h = h + A_COEF * (rec + inp - h);   // (1-a)h + a(rec+inp)
        hb[t * NN + n] = h;
    }
}

// out[b,t,o] = sum_n Out_w[o,n] * tanh(hidden[b,t,n])
// One wave per row, ROWS_PER_WAVE rows per wave to amortize Out_w loads.
#define ROWS_PER_WAVE 16
__global__ __launch_bounds__(256) void out_kernel(
    const float* __restrict__ hidden,  // [B*T, N]
    const float* __restrict__ Out_w,   // [OUTC, N]
    float* __restrict__ out)           // [B*T, OUTC]
{
    const int lane = threadIdx.x & 63;
    const int wave = threadIdx.x >> 6;
    const int wave_global = blockIdx.x * 4 + wave;

    // lane covers n = lane*8 .. lane*8+7 for all 8 outputs
    float Ow[OUTC][8];
    #pragma unroll
    for (int o = 0; o < OUTC; ++o) {
        float4 w0 = *(const float4*)&Out_w[o * NN + lane * 8];
        float4 w1 = *(const float4*)&Out_w[o * NN + lane * 8 + 4];
        Ow[o][0] = w0.x; Ow[o][1] = w0.y; Ow[o][2] = w0.z; Ow[o][3] = w0.w;
        Ow[o][4] = w1.x; Ow[o][5] = w1.y; Ow[o][6] = w1.z; Ow[o][7] = w1.w;
    }

    #pragma unroll 1
    for (int rw = 0; rw < ROWS_PER_WAVE; ++rw) {
        const int row = wave_global * ROWS_PER_WAVE + rw;
        const float* hr = hidden + (size_t)row * NN + lane * 8;
        float4 a0 = *(const float4*)&hr[0];
        float4 a1 = *(const float4*)&hr[4];
        float p[8];
        p[0] = fast_tanh(a0.x); p[1] = fast_tanh(a0.y);
        p[2] = fast_tanh(a0.z); p[3] = fast_tanh(a0.w);
        p[4] = fast_tanh(a1.x); p[5] = fast_tanh(a1.y);
        p[6] = fast_tanh(a1.z); p[7] = fast_tanh(a1.w);

        float acc[OUTC];
        #pragma unroll
        for (int o = 0; o < OUTC; ++o) {
            float s = Ow[o][0] * p[0];
            #pragma unroll
            for (int j = 1; j < 8; ++j) s = fmaf(Ow[o][j], p[j], s);
            acc[o] = s;
        }
        // stage 1: butterfly xor 1,2,4 on all 8 accs -> 8-lane group sums
        #pragma unroll
        for (int m = 1; m < 8; m <<= 1)
            #pragma unroll
            for (int o = 0; o < OUTC; ++o)
                acc[o] += __shfl_xor(acc[o], m, 64);
        // each lane picks its designated output index
        const int oo = lane & 7;
        float s = acc[0];
        s = (oo == 1) ? acc[1] : s;
        s = (oo == 2) ? acc[2] : s;
        s = (oo == 3) ? acc[3] : s;
        s = (oo == 4) ? acc[4] : s;
        s = (oo == 5) ? acc[5] : s;
        s = (oo == 6) ? acc[6] : s;
        s = (oo == 7) ? acc[7] : s;
        // stage 2: combine the 8 groups
        #pragma unroll
        for (int m = 8; m < 64; m <<= 1)
            s += __shfl_xor(s, m, 64);
        if (lane < OUTC)
            out[(size_t)row * OUTC + lane] = s;
    }
}

extern "C" void kernel_launch(void* const* d_in, const int* in_sizes, int n_in,
                              void* d_out, int out_size, void* d_ws, size_t ws_size,
                              hipStream_t stream) {
    const float* x    = (const float*)d_in[0];  // [64,1024,16]
    const float* In_w = (const float*)d_in[1];  // [512,16]
    const float* V_w  = (const float*)d_in[2];  // [16,512]
    const float* U_w  = (const float*)d_in[3];  // [512,16]
    const float* Ow   = (const float*)d_in[4];  // [8,512]
    const float* h0   = (const float*)d_in[5];  // [512]

    float* hidden = (float*)d_out;                         // [64,1024,512]
    float* out    = hidden + (size_t)BATCH * TT * NN;      // [64,1024,8]

    scan_kernel<<<BATCH, 512, 0, stream>>>(x, In_w, V_w, U_w, h0, hidden);

    // 65536 rows / (16 rows/wave) = 4096 waves / 4 waves/block = 1024 blocks
    out_kernel<<<1024, 256, 0, stream>>>(hidden, Ow, out);
}

// Round 2
// 1068.205 us; speedup vs baseline: 1.0296x; 1.0296x over previous
//
#include <hip/hip_runtime.h>

#define BATCH 64
#define TT    1024
#define INC   16
#define NN    512
#define RNK   16
#define OUTC  8

// a = DT/TAU = 0.1
#define A_COEF 0.1f

__device__ __forceinline__ float fast_tanh(float x) {
    // tanh(x) = 1 - 2/(exp(2x)+1); safe at +/-inf
    float e = __expf(2.0f * x);
    return 1.0f - __fdividef(2.0f, e + 1.0f);
}

// Barrier with LDS ordering only. Deliberately does NOT drain vmcnt:
// the only VMEM ops in flight are per-lane-private global stores of h/out
// (never read in-kernel) and the read-only weight loads done before the
// first full __syncthreads(). Keeping stores in flight removes ~600 cyc of
// HBM store-ack latency from every step's critical path.
__device__ __forceinline__ void lgkm_barrier() {
    asm volatile("s_waitcnt lgkmcnt(0)\n\ts_barrier" ::: "memory");
}

// One block per batch element. 512 threads = 8 waves, one lane per state n.
// All weights in registers for the whole scan; x staged in LDS once;
// phi and low round-trip LDS with lgkm-only barriers.
__global__ __launch_bounds__(512, 1) void scan_kernel(
    const float* __restrict__ x,      // [B,T,INC]
    const float* __restrict__ In_w,   // [N,INC]
    const float* __restrict__ V_w,    // [R,N]
    const float* __restrict__ U_w,    // [N,R]
    const float* __restrict__ Out_w,  // [OUTC,N]
    const float* __restrict__ h0,     // [N]
    float* __restrict__ hidden,       // [B,T,N]
    float* __restrict__ out)          // [B,T,OUTC]
{
    const int b   = blockIdx.x;
    const int tid = threadIdx.x;
    const int rr  = tid >> 5;   // low-rank reduce: which r this lane serves
    const int g   = tid & 31;   // position within the 32-lane reduce group
    const int ow  = tid >> 6;   // out reduce: wave w computes output w
    const int p   = tid & 63;   // lane within wave

    __shared__ __align__(16) float xs[TT * INC];  // 64 KB: whole x[b]
    __shared__ __align__(16) float phi_s[NN];
    __shared__ __align__(16) float low_s[RNK];

    // ---- stage x[b] (64 KB) into LDS, coalesced float4 ----
    {
        const float4* src = (const float4*)(x + (size_t)b * TT * INC);
        float4* dst = (float4*)xs;
        #pragma unroll
        for (int c = 0; c < 8; ++c)
            dst[c * 512 + tid] = src[c * 512 + tid];
    }

    // ---- per-lane weights in registers ----
    float Ur[RNK];
    #pragma unroll
    for (int r = 0; r < RNK; ++r) Ur[r] = U_w[tid * RNK + r];

    float Wr[INC];
    #pragma unroll
    for (int i = 0; i < INC; ++i) Wr[i] = In_w[tid * INC + i];

    // V fragment: lane (rr,g) covers n' = k*128 + g*4 + j
    float Vr[16];
    #pragma unroll
    for (int k = 0; k < 4; ++k)
        #pragma unroll
        for (int j = 0; j < 4; ++j)
            Vr[k * 4 + j] = V_w[rr * NN + k * 128 + g * 4 + j];

    // Out_w fragment: wave ow, lane p covers n = p*8 .. p*8+7
    float Owr[8];
    #pragma unroll
    for (int j = 0; j < 8; ++j) Owr[j] = Out_w[ow * NN + p * 8 + j];

    float h = h0[tid];

    __syncthreads();  // full drain once: staging + weight loads visible

    float* hb = hidden + (size_t)b * TT * NN;
    float* ob = out + (size_t)b * TT * OUTC;

    // x for t=0 (from LDS)
    float4 xv0, xv1, xv2, xv3;
    {
        const float4* xp = (const float4*)xs;
        xv0 = xp[0]; xv1 = xp[1]; xv2 = xp[2]; xv3 = xp[3];
    }

    for (int t = 0; t < TT; ++t) {
        float phi = fast_tanh(h);
        phi_s[tid] = phi;

        // input projection with current x (independent of phi chain, 4-acc tree)
        float ia = Wr[0] * xv0.x;
        float ib = Wr[1] * xv0.y;
        float ic = Wr[2] * xv0.z;
        float id = Wr[3] * xv0.w;
        ia = fmaf(Wr[4],  xv1.x, ia);
        ib = fmaf(Wr[5],  xv1.y, ib);
        ic = fmaf(Wr[6],  xv1.z, ic);
        id = fmaf(Wr[7],  xv1.w, id);
        ia = fmaf(Wr[8],  xv2.x, ia);
        ib = fmaf(Wr[9],  xv2.y, ib);
        ic = fmaf(Wr[10], xv2.z, ic);
        id = fmaf(Wr[11], xv2.w, id);
        ia = fmaf(Wr[12], xv3.x, ia);
        ib = fmaf(Wr[13], xv3.y, ib);
        ic = fmaf(Wr[14], xv3.z, ic);
        id = fmaf(Wr[15], xv3.w, id);
        float inp = (ia + ib) + (ic + id);

        lgkm_barrier();   // phi visible

        // prefetch x for t+1 (consumed next iteration; drains at barrier2)
        {
            int tn = (t + 1 < TT) ? t + 1 : t;
            const float4* xp = (const float4*)(xs + tn * INC);
            xv0 = xp[0]; xv1 = xp[1]; xv2 = xp[2]; xv3 = xp[3];
        }

        // ---- low[rr] partial over this lane's 16 n's (4-acc tree) ----
        float p0 = 0.f, p1 = 0.f, p2 = 0.f, p3 = 0.f;
        #pragma unroll
        for (int k = 0; k < 4; ++k) {
            float4 ph = *(const float4*)&phi_s[k * 128 + g * 4];
            p0 = fmaf(Vr[k * 4 + 0], ph.x, p0);
            p1 = fmaf(Vr[k * 4 + 1], ph.y, p1);
            p2 = fmaf(Vr[k * 4 + 2], ph.z, p2);
            p3 = fmaf(Vr[k * 4 + 3], ph.w, p3);
        }
        float partial = (p0 + p1) + (p2 + p3);
        #pragma unroll
        for (int m = 1; m < 32; m <<= 1)
            partial += __shfl_xor(partial, m, 64);
        if (g == 0) low_s[rr] = partial;

        // ---- out[b,t-1,ow] partial (independent chain, overlaps butterfly) ----
        float4 q0 = *(const float4*)&phi_s[p * 8];
        float4 q1 = *(const float4*)&phi_s[p * 8 + 4];
        float oa = Owr[0] * q0.x;
        float obb = Owr[1] * q0.y;
        float oc = Owr[2] * q0.z;
        float od = Owr[3] * q0.w;
        oa  = fmaf(Owr[4], q1.x, oa);
        obb = fmaf(Owr[5], q1.y, obb);
        oc  = fmaf(Owr[6], q1.z, oc);
        od  = fmaf(Owr[7], q1.w, od);
        float osum = (oa + obb) + (oc + od);
        #pragma unroll
        for (int m = 1; m < 64; m <<= 1)
            osum += __shfl_xor(osum, m, 64);
        if (t > 0 && p == 0)
            ob[(t - 1) * OUTC + ow] = osum;

        lgkm_barrier();   // low visible

        // ---- rec = U[n,:] . low (4-acc tree) ----
        float4 l0 = *(const float4*)&low_s[0];
        float4 l1 = *(const float4*)&low_s[4];
        float4 l2 = *(const float4*)&low_s[8];
        float4 l3 = *(const float4*)&low_s[12];
        float ra = Ur[0] * l0.x;
        float rb = Ur[1] * l0.y;
        float rc = Ur[2] * l0.z;
        float rd = Ur[3] * l0.w;
        ra = fmaf(Ur[4],  l1.x, ra);
        rb = fmaf(Ur[5],  l1.y, rb);
        rc = fmaf(Ur[6],  l1.z, rc);
        rd = fmaf(Ur[7],  l1.w, rd);
        ra = fmaf(Ur[8],  l2.x, ra);
        rb = fmaf(Ur[9],  l2.y, rb);
        rc = fmaf(Ur[10], l2.z, rc);
        rd = fmaf(Ur[11], l2.w, rd);
        ra = fmaf(Ur[12], l3.x, ra);
        rb = fmaf(Ur[13], l3.y, rb);
        rc = fmaf(Ur[14], l3.z, rc);
        rd = fmaf(Ur[15], l3.w, rd);
        float rec = (ra + rb) + (rc + rd);

        h = fmaf(A_COEF, (rec + inp) - h, h);   // (1-a)h + a(rec+inp)
        hb[t * NN + tid] = h;                   // fire-and-forget (never drained)
    }

    // ---- epilogue: out[b, TT-1, :] uses tanh of the final h ----
    float phi = fast_tanh(h);
    phi_s[tid] = phi;
    lgkm_barrier();
    {
        float4 q0 = *(const float4*)&phi_s[p * 8];
        float4 q1 = *(const float4*)&phi_s[p * 8 + 4];
        float oa = Owr[0] * q0.x;
        float obb = Owr[1] * q0.y;
        float oc = Owr[2] * q0.z;
        float od = Owr[3] * q0.w;
        oa  = fmaf(Owr[4], q1.x, oa);
        obb = fmaf(Owr[5], q1.y, obb);
        oc  = fmaf(Owr[6], q1.z, oc);
        od  = fmaf(Owr[7], q1.w, od);
        float osum = (oa + obb) + (oc + od);
        #pragma unroll
        for (int m = 1; m < 64; m <<= 1)
            osum += __shfl_xor(osum, m, 64);
        if (p == 0)
            ob[(TT - 1) * OUTC + ow] = osum;
    }
}

extern "C" void kernel_launch(void* const* d_in, const int* in_sizes, int n_in,
                              void* d_out, int out_size, void* d_ws, size_t ws_size,
                              hipStream_t stream) {
    const float* x    = (const float*)d_in[0];  // [64,1024,16]
    const float* In_w = (const float*)d_in[1];  // [512,16]
    const float* V_w  = (const float*)d_in[2];  // [16,512]
    const float* U_w  = (const float*)d_in[3];  // [512,16]
    const float* Ow   = (const float*)d_in[4];  // [8,512]
    const float* h0   = (const float*)d_in[5];  // [512]

    float* hidden = (float*)d_out;                         // [64,1024,512]
    float* out    = hidden + (size_t)BATCH * TT * NN;      // [64,1024,8]

    scan_kernel<<<BATCH, 512, 0, stream>>>(x, In_w, V_w, U_w, Ow, h0, hidden, out);
}

// Round 4
// 810.533 us; speedup vs baseline: 1.3569x; 1.3179x over previous
//
#include <hip/hip_runtime.h>

#define BATCH 64
#define TT    1024
#define INC   16
#define NN    512
#define RNK   16
#define OUTC  8

// a = DT/TAU = 0.1
#define A_COEF 0.1f

__device__ __forceinline__ float fast_tanh(float x) {
    // tanh(x) = 1 - 2/(exp(2x)+1); safe at +/-inf
    float e = __expf(2.0f * x);
    return 1.0f - __fdividef(2.0f, e + 1.0f);
}

// Barrier with LDS ordering only (does NOT drain vmcnt: h/out stores are
// fire-and-forget, never read in-kernel).
__device__ __forceinline__ void lgkm_barrier() {
    asm volatile("s_waitcnt lgkmcnt(0)\n\ts_barrier" ::: "memory");
}

// ---- DPP cross-lane adds (VALU pipe, ~4-8 cyc/stage vs ~100 for ds_bpermute) ----
// dpp_ctrl: row_shr:N = 0x110+N, row_bcast15 = 0x142, row_bcast31 = 0x143
template<int CTRL>
__device__ __forceinline__ float dpp_add(float x) {
    int y = __builtin_amdgcn_update_dpp(0, __float_as_int(x), CTRL, 0xF, 0xF, true);
    return x + __int_as_float(y);
}

// Sum over each 32-lane half-wave; result valid in lanes 31 and 63.
// (validated in R3: hidden output passed using this)
__device__ __forceinline__ float half_wave_sum(float x) {
    x = dpp_add<0x111>(x);  // row_shr:1
    x = dpp_add<0x112>(x);  // row_shr:2
    x = dpp_add<0x114>(x);  // row_shr:4
    x = dpp_add<0x118>(x);  // row_shr:8  -> row sums at lanes 15/31/47/63
    x = dpp_add<0x142>(x);  // row_bcast15 -> 32-group sums at lanes 31/63
    return x;
}

// Full 64-lane sum; result valid in lane 63.
__device__ __forceinline__ float wave_sum(float x) {
    x = half_wave_sum(x);
    x = dpp_add<0x143>(x);  // row_bcast31 -> total at lane 63
    return x;
}

// One block per batch element. 512 threads = 8 waves, one lane per state n.
// All weights in registers for the whole scan; x staged in LDS once;
// phi and low round-trip LDS with lgkm-only barriers; reduces via DPP.
__global__ __launch_bounds__(512, 1) void scan_kernel(
    const float* __restrict__ x,      // [B,T,INC]
    const float* __restrict__ In_w,   // [N,INC]
    const float* __restrict__ V_w,    // [R,N]
    const float* __restrict__ U_w,    // [N,R]
    const float* __restrict__ Out_w,  // [OUTC,N]
    const float* __restrict__ h0,     // [N]
    float* __restrict__ hidden,       // [B,T,N]
    float* __restrict__ out)          // [B,T,OUTC]
{
    const int b   = blockIdx.x;
    const int tid = threadIdx.x;
    const int rr  = tid >> 5;   // low-rank reduce: which r this lane serves
    const int g   = tid & 31;   // position within the 32-lane reduce group
    const int ow  = tid >> 6;   // out reduce: wave w computes output w
    const int p   = tid & 63;   // lane within wave

    __shared__ __align__(16) float xs[TT * INC];  // 64 KB: whole x[b]
    __shared__ __align__(16) float phi_s[NN];
    __shared__ __align__(16) float low_s[RNK];

    // ---- stage x[b] (64 KB) into LDS, coalesced float4 ----
    {
        const float4* src = (const float4*)(x + (size_t)b * TT * INC);
        float4* dst = (float4*)xs;
        #pragma unroll
        for (int c = 0; c < 8; ++c)
            dst[c * 512 + tid] = src[c * 512 + tid];
    }

    // ---- per-lane weights in registers ----
    float Ur[RNK];
    #pragma unroll
    for (int r = 0; r < RNK; ++r) Ur[r] = U_w[tid * RNK + r];

    float Wr[INC];
    #pragma unroll
    for (int i = 0; i < INC; ++i) Wr[i] = In_w[tid * INC + i];

    // V fragment: lane (rr,g) covers n' = k*128 + g*4 + j
    float Vr[16];
    #pragma unroll
    for (int k = 0; k < 4; ++k)
        #pragma unroll
        for (int j = 0; j < 4; ++j)
            Vr[k * 4 + j] = V_w[rr * NN + k * 128 + g * 4 + j];

    // Out_w fragment: wave ow, lane p covers n = p*8 .. p*8+7
    float Owr[8];
    #pragma unroll
    for (int j = 0; j < 8; ++j) Owr[j] = Out_w[ow * NN + p * 8 + j];

    float h = h0[tid];

    __syncthreads();  // full drain once: staging + weight loads visible

    float* hb = hidden + (size_t)b * TT * NN;
    float* ob = out + (size_t)b * TT * OUTC;

    // x for t=0 (from LDS)
    float4 xv0, xv1, xv2, xv3;
    {
        const float4* xp = (const float4*)xs;
        xv0 = xp[0]; xv1 = xp[1]; xv2 = xp[2]; xv3 = xp[3];
    }

    for (int t = 0; t < TT; ++t) {
        float phi = fast_tanh(h);
        phi_s[tid] = phi;

        // input projection with current x (independent of phi chain, 4-acc tree)
        float ia = Wr[0] * xv0.x;
        float ib = Wr[1] * xv0.y;
        float ic = Wr[2] * xv0.z;
        float id = Wr[3] * xv0.w;
        ia = fmaf(Wr[4],  xv1.x, ia);
        ib = fmaf(Wr[5],  xv1.y, ib);
        ic = fmaf(Wr[6],  xv1.z, ic);
        id = fmaf(Wr[7],  xv1.w, id);
        ia = fmaf(Wr[8],  xv2.x, ia);
        ib = fmaf(Wr[9],  xv2.y, ib);
        ic = fmaf(Wr[10], xv2.z, ic);
        id = fmaf(Wr[11], xv2.w, id);
        ia = fmaf(Wr[12], xv3.x, ia);
        ib = fmaf(Wr[13], xv3.y, ib);
        ic = fmaf(Wr[14], xv3.z, ic);
        id = fmaf(Wr[15], xv3.w, id);
        float inp = (ia + ib) + (ic + id);

        lgkm_barrier();   // phi visible

        // ---- low[rr] partial over this lane's 16 n's (4-acc tree) ----
        float p0 = 0.f, p1 = 0.f, p2 = 0.f, p3 = 0.f;
        #pragma unroll
        for (int k = 0; k < 4; ++k) {
            float4 ph = *(const float4*)&phi_s[k * 128 + g * 4];
            p0 = fmaf(Vr[k * 4 + 0], ph.x, p0);
            p1 = fmaf(Vr[k * 4 + 1], ph.y, p1);
            p2 = fmaf(Vr[k * 4 + 2], ph.z, p2);
            p3 = fmaf(Vr[k * 4 + 3], ph.w, p3);
        }
        float partial = (p0 + p1) + (p2 + p3);
        partial = half_wave_sum(partial);          // DPP
        if (g == 31) low_s[rr] = partial;          // lanes 31/63 of each wave

        // prefetch x for t+1 (consumed next iteration; drains at barrier2)
        {
            int tn = (t + 1 < TT) ? t + 1 : t;
            const float4* xp = (const float4*)(xs + tn * INC);
            xv0 = xp[0]; xv1 = xp[1]; xv2 = xp[2]; xv3 = xp[3];
        }

        // ---- out[b,t-1,ow]: phi_t = tanh(h_{t-1}) is the post-state of step t-1 ----
        float4 q0 = *(const float4*)&phi_s[p * 8];
        float4 q1 = *(const float4*)&phi_s[p * 8 + 4];
        float oa = Owr[0] * q0.x;
        float obb = Owr[1] * q0.y;
        float oc = Owr[2] * q0.z;
        float od = Owr[3] * q0.w;
        oa  = fmaf(Owr[4], q1.x, oa);
        obb = fmaf(Owr[5], q1.y, obb);
        oc  = fmaf(Owr[6], q1.z, oc);
        od  = fmaf(Owr[7], q1.w, od);
        float osum = (oa + obb) + (oc + od);
        osum = wave_sum(osum);                     // DPP
        if (t > 0 && p == 63)
            ob[(t - 1) * OUTC + ow] = osum;

        lgkm_barrier();   // low visible

        // ---- rec = U[n,:] . low (4-acc tree) ----
        float4 l0 = *(const float4*)&low_s[0];
        float4 l1 = *(const float4*)&low_s[4];
        float4 l2 = *(const float4*)&low_s[8];
        float4 l3 = *(const float4*)&low_s[12];
        float ra = Ur[0] * l0.x;
        float rb = Ur[1] * l0.y;
        float rc = Ur[2] * l0.z;
        float rd = Ur[3] * l0.w;
        ra = fmaf(Ur[4],  l1.x, ra);
        rb = fmaf(Ur[5],  l1.y, rb);
        rc = fmaf(Ur[6],  l1.z, rc);
        rd = fmaf(Ur[7],  l1.w, rd);
        ra = fmaf(Ur[8],  l2.x, ra);
        rb = fmaf(Ur[9],  l2.y, rb);
        rc = fmaf(Ur[10], l2.z, rc);
        rd = fmaf(Ur[11], l2.w, rd);
        ra = fmaf(Ur[12], l3.x, ra);
        rb = fmaf(Ur[13], l3.y, rb);
        rc = fmaf(Ur[14], l3.z, rc);
        rd = fmaf(Ur[15], l3.w, rd);
        float rec = (ra + rb) + (rc + rd);

        h = fmaf(A_COEF, (rec + inp) - h, h);   // (1-a)h + a(rec+inp)
        hb[t * NN + tid] = h;                   // fire-and-forget (never drained)
    }

    // ---- epilogue: out[b, TT-1, :] uses tanh of the final h ----
    float phi = fast_tanh(h);
    phi_s[tid] = phi;
    lgkm_barrier();
    {
        float4 q0 = *(const float4*)&phi_s[p * 8];
        float4 q1 = *(const float4*)&phi_s[p * 8 + 4];
        float oa = Owr[0] * q0.x;
        float obb = Owr[1] * q0.y;
        float oc = Owr[2] * q0.z;
        float od = Owr[3] * q0.w;
        oa  = fmaf(Owr[4], q1.x, oa);
        obb = fmaf(Owr[5], q1.y, obb);
        oc  = fmaf(Owr[6], q1.z, oc);
        od  = fmaf(Owr[7], q1.w, od);
        float osum = (oa + obb) + (oc + od);
        osum = wave_sum(osum);
        if (p == 63)
            ob[(TT - 1) * OUTC + ow] = osum;
    }
}

extern "C" void kernel_launch(void* const* d_in, const int* in_sizes, int n_in,
                              void* d_out, int out_size, void* d_ws, size_t ws_size,
                              hipStream_t stream) {
    const float* x    = (const float*)d_in[0];  // [64,1024,16]
    const float* In_w = (const float*)d_in[1];  // [512,16]
    const float* V_w  = (const float*)d_in[2];  // [16,512]
    const float* U_w  = (const float*)d_in[3];  // [512,16]
    const float* Ow   = (const float*)d_in[4];  // [8,512]
    const float* h0   = (const float*)d_in[5];  // [512]

    float* hidden = (float*)d_out;                         // [64,1024,512]
    float* out    = hidden + (size_t)BATCH * TT * NN;      // [64,1024,8]

    scan_kernel<<<BATCH, 512, 0, stream>>>(x, In_w, V_w, U_w, Ow, h0, hidden, out);
}